// Round 1
// 1517.943 us; speedup vs baseline: 1.0638x; 1.0638x over previous
//
#include <hip/hip_runtime.h>
#include <cstdint>
#include <cstddef>

// ---------------------------------------------------------------------------
// TED forward on MI355X. Round 2: global_load_lds (width=16) staging in all
// MFMA kernels (gemm_bt + decay). LDS layouts were already linear in t*16
// bytes, satisfying the wave-uniform-base + lane*16 constraint (m104).
//   - bf16 MFMA (16x16x32) GEMMs with fused epilogues
//   - decay einsum as triangular GEMM with in-register A-fragment (exp2),
//     exp2 VALU work now overlaps the async Q staging
//   - fp32 kept for: residual x, rmsnorm stats, nl (decay log-rate), epilogues
// ---------------------------------------------------------------------------

typedef __bf16 bf16_t;
typedef __bf16 bf16x2 __attribute__((ext_vector_type(2)));
typedef __bf16 bf16x4 __attribute__((ext_vector_type(4)));
typedef __bf16 bf16x8 __attribute__((ext_vector_type(8)));
typedef float  f32x4  __attribute__((ext_vector_type(4)));

#define TED_DIM   512
#define TED_HID   2048
#define TED_L     4
#define TED_VOCAB 32000
#define TED_B     2
#define TED_S     2048
#define TED_ROWS  4096   // B*S
#define LOG2E     1.44269504088896340736f

// async global -> LDS, 16 bytes per lane (m97: the +69% lever)
#define GLDS16(gp, lp)                                                  \
    __builtin_amdgcn_global_load_lds(                                   \
        (__attribute__((address_space(1))) void*)(gp),                  \
        (__attribute__((address_space(3))) void*)(lp), 16, 0, 0)

// ---------------------------------------------------------------------------
// fp32 -> bf16 convert (grid-stride over float4)
// ---------------------------------------------------------------------------
__global__ void cvt_kernel(const float* __restrict__ in, bf16_t* __restrict__ out, int n4)
{
    int i = blockIdx.x * blockDim.x + threadIdx.x;
    if (i < n4) {
        float4 v = ((const float4*)in)[i];
        bf16x4 o;
        o[0] = (bf16_t)v.x; o[1] = (bf16_t)v.y; o[2] = (bf16_t)v.z; o[3] = (bf16_t)v.w;
        ((bf16x4*)out)[i] = o;
    }
}

// ---------------------------------------------------------------------------
// embedding gather: x[r,:] = emb[tok[r],:]   (fp32, 128 threads/row)
// ---------------------------------------------------------------------------
__global__ void embed_kernel(const int* __restrict__ tok, const float* __restrict__ emb,
                             float* __restrict__ x)
{
    int r = blockIdx.x;
    int t = threadIdx.x;           // 0..127, 4 floats each
    int id = tok[r];
    float4 v = *(const float4*)&emb[(size_t)id * TED_DIM + t * 4];
    *(float4*)&x[(size_t)r * TED_DIM + t * 4] = v;
}

// ---------------------------------------------------------------------------
// rmsnorm (+ optional fused lambda projection -> nl2 = log_sigmoid(h.lam)*log2e)
// one block (256 thr) per row of 512
// ---------------------------------------------------------------------------
__global__ void rmsnorm_kernel(const float* __restrict__ x, const float* __restrict__ w,
                               const float* __restrict__ lam,
                               bf16_t* __restrict__ hout, float* __restrict__ nl2out)
{
    int row = blockIdx.x;
    int t = threadIdx.x;
    int lane = t & 63, wv = t >> 6;
    const float* xr = x + (size_t)row * TED_DIM;

    float2 v = *(const float2*)&xr[t * 2];
    float ss = v.x * v.x + v.y * v.y;
    #pragma unroll
    for (int off = 32; off; off >>= 1) ss += __shfl_down(ss, off, 64);

    __shared__ float red[4];
    __shared__ float sscale;
    if (lane == 0) red[wv] = ss;
    __syncthreads();
    if (t == 0) {
        float s = red[0] + red[1] + red[2] + red[3];
        sscale = rsqrtf(s * (1.0f / (float)TED_DIM) + 1e-6f);
    }
    __syncthreads();
    float scale = sscale;

    float2 wv2 = *(const float2*)&w[t * 2];
    float h0 = v.x * scale * wv2.x;
    float h1 = v.y * scale * wv2.y;
    bf16x2 hb; hb[0] = (bf16_t)h0; hb[1] = (bf16_t)h1;
    *(bf16x2*)&hout[(size_t)row * TED_DIM + t * 2] = hb;

    if (lam != nullptr) {
        float2 l2 = *(const float2*)&lam[t * 2];
        float p = h0 * l2.x + h1 * l2.y;
        #pragma unroll
        for (int off = 32; off; off >>= 1) p += __shfl_down(p, off, 64);
        if (lane == 0) red[wv] = p;
        __syncthreads();
        if (t == 0) {
            float z = red[0] + red[1] + red[2] + red[3];
            float nl = fminf(z, 0.0f) - log1pf(__expf(-fabsf(z)));  // log_sigmoid(z)
            nl2out[row] = nl * LOG2E;
        }
    }
}

// ---------------------------------------------------------------------------
// bf16 GEMM, B^T layout: out[m,n] = sum_k A[m,k] * B[n,k]
// A: [M,K] row-major bf16, B: [N,K] row-major bf16. BK=32, 256 threads.
// Staging via global_load_lds width=16: thread t's LDS dest byte offset is
// exactly 16*t (wave-uniform base + lane*16) -> legal for direct-to-LDS DMA.
// Epilogues fused via EPI template param.
// ---------------------------------------------------------------------------
enum { EPI_BF16 = 0, EPI_F32 = 1, EPI_GMUL_ADDX = 2, EPI_ADDX = 3, EPI_SILUMUL = 4 };

template <int BM, int BN, int EPI>
__global__ __launch_bounds__(256)
void gemm_bt(const bf16_t* __restrict__ A, const bf16_t* __restrict__ B,
             int M, int N, int K,
             float* __restrict__ outf, bf16_t* __restrict__ outb,
             const float* __restrict__ gmul, const bf16_t* __restrict__ umul,
             float* __restrict__ xres)
{
    constexpr int TM = BM / 32, TN = BN / 32;
    __shared__ __align__(16) bf16_t sA[BM * 32];
    __shared__ __align__(16) bf16_t sB[BN * 32];

    int t = threadIdx.x;
    int lane = t & 63, w = t >> 6;
    int quad = lane >> 4, l16 = lane & 15;
    int m0 = blockIdx.y * BM, n0 = blockIdx.x * BN;
    int wm = (w & 1) * (BM / 2), wn = (w >> 1) * (BN / 2);
    int srow = t >> 2, skc = t & 3;   // staging: row 0..63 per issue, 16B k-chunk

    f32x4 acc[TM][TN] = {};

    for (int k0 = 0; k0 < K; k0 += 32) {
        #pragma unroll
        for (int i = 0; i < BM / 64; i++) {
            int r = i * 64 + srow;
            GLDS16(&A[(size_t)(m0 + r) * K + k0 + skc * 8], &sA[r * 32 + skc * 8]);
        }
        #pragma unroll
        for (int i = 0; i < BN / 64; i++) {
            int r = i * 64 + srow;
            GLDS16(&B[(size_t)(n0 + r) * K + k0 + skc * 8], &sB[r * 32 + skc * 8]);
        }
        __syncthreads();   // compiler drains vmcnt before s_barrier
        bf16x8 af[TM], bfr[TN];
        #pragma unroll
        for (int i = 0; i < TM; i++)
            af[i] = *(const bf16x8*)&sA[(wm + i * 16 + l16) * 32 + quad * 8];
        #pragma unroll
        for (int j = 0; j < TN; j++)
            bfr[j] = *(const bf16x8*)&sB[(wn + j * 16 + l16) * 32 + quad * 8];
        #pragma unroll
        for (int i = 0; i < TM; i++)
            #pragma unroll
            for (int j = 0; j < TN; j++)
                acc[i][j] = __builtin_amdgcn_mfma_f32_16x16x32_bf16(af[i], bfr[j], acc[i][j], 0, 0, 0);
        __syncthreads();
    }

    // epilogue: C/D layout col = lane&15, row = quad*4 + r  [m89/m91 verified]
    #pragma unroll
    for (int i = 0; i < TM; i++) {
        #pragma unroll
        for (int j = 0; j < TN; j++) {
            int col = n0 + wn + j * 16 + l16;
            #pragma unroll
            for (int r = 0; r < 4; r++) {
                int rowg = m0 + wm + i * 16 + quad * 4 + r;
                size_t idx = (size_t)rowg * N + col;
                float v = acc[i][j][r];
                if constexpr (EPI == EPI_BF16) {
                    outb[idx] = (bf16_t)v;
                } else if constexpr (EPI == EPI_F32) {
                    outf[idx] = v;
                } else if constexpr (EPI == EPI_GMUL_ADDX) {
                    xres[idx] += v * gmul[idx];
                } else if constexpr (EPI == EPI_ADDX) {
                    xres[idx] += v;
                } else { // EPI_SILUMUL: t = u * silu(v)
                    float u = (float)umul[idx];
                    float s = v / (1.0f + __expf(-v));
                    outb[idx] = (bf16_t)(u * s);
                }
            }
        }
    }
}

template <int BM, int BN, int EPI>
static void launch_gemm(hipStream_t s, const bf16_t* A, const bf16_t* B,
                        int M, int N, int K,
                        float* outf = nullptr, bf16_t* outb = nullptr,
                        const float* gmul = nullptr, const bf16_t* umul = nullptr,
                        float* xres = nullptr)
{
    dim3 grid(N / BN, M / BM);
    gemm_bt<BM, BN, EPI><<<grid, 256, 0, s>>>(A, B, M, N, K, outf, outb, gmul, umul, xres);
}

// ---------------------------------------------------------------------------
// decay einsum: aout[b*S+i, d] = silu( sum_{j<=i} exp2(nl2[b*S+j]*(i-j)) * q[b,j,d] )
// q supplied transposed: qT[d, b*S+j]  ([DIM, ROWS] row-major bf16)
// block: 64 i-rows x 128 d-cols, A-fragment (decay) computed in-registers.
// Q staging via global_load_lds -> exp2 fragment compute overlaps the DMA.
// ---------------------------------------------------------------------------
__global__ __launch_bounds__(256)
void decay_kernel(const bf16_t* __restrict__ qT, const float* __restrict__ nl2,
                  bf16_t* __restrict__ aout)
{
    constexpr int BI = 64, BD = 128;
    __shared__ __align__(16) bf16_t sQ[BD * 32];

    int t = threadIdx.x;
    int lane = t & 63, w = t >> 6;
    int quad = lane >> 4, l16 = lane & 15;
    int d0 = blockIdx.x * BD;
    int i0 = blockIdx.y * BI;
    int b  = blockIdx.z;
    int wm = (w & 1) * 32, wn = (w >> 1) * 64;   // TM=2, TN=4
    int srow = t >> 2, skc = t & 3;

    f32x4 acc[2][4] = {};

    int jt_end = i0 + BI;   // causal: j <= i0+63
    for (int j0 = 0; j0 < jt_end; j0 += 32) {
        #pragma unroll
        for (int i = 0; i < 2; i++) {
            int r = i * 64 + srow;
            GLDS16(&qT[(size_t)(d0 + r) * TED_ROWS + b * TED_S + j0 + skc * 8],
                   &sQ[r * 32 + skc * 8]);
        }
        // decay A-fragments in registers (overlaps the async LDS DMA):
        // A[m=l16][k=quad*8+jj]
        float4 nA = *(const float4*)&nl2[b * TED_S + j0 + quad * 8];
        float4 nB = *(const float4*)&nl2[b * TED_S + j0 + quad * 8 + 4];
        float nn[8] = {nA.x, nA.y, nA.z, nA.w, nB.x, nB.y, nB.z, nB.w};
        bf16x8 af[2];
        #pragma unroll
        for (int i = 0; i < 2; i++) {
            int mi = i0 + wm + i * 16 + l16;
            #pragma unroll
            for (int jj = 0; jj < 8; jj++) {
                int j = j0 + quad * 8 + jj;
                int tt = mi - j;
                float dv = (tt >= 0) ? exp2f(nn[jj] * (float)tt) : 0.0f;
                af[i][jj] = (bf16_t)dv;
            }
        }
        __syncthreads();
        bf16x8 bfr[4];
        #pragma unroll
        for (int j = 0; j < 4; j++)
            bfr[j] = *(const bf16x8*)&sQ[(wn + j * 16 + l16) * 32 + quad * 8];
        #pragma unroll
        for (int i = 0; i < 2; i++)
            #pragma unroll
            for (int j = 0; j < 4; j++)
                acc[i][j] = __builtin_amdgcn_mfma_f32_16x16x32_bf16(af[i], bfr[j], acc[i][j], 0, 0, 0);
        __syncthreads();
    }

    #pragma unroll
    for (int i = 0; i < 2; i++) {
        #pragma unroll
        for (int j = 0; j < 4; j++) {
            int d = d0 + wn + j * 16 + l16;
            #pragma unroll
            for (int r = 0; r < 4; r++) {
                int ig = i0 + wm + i * 16 + quad * 4 + r;
                float v = acc[i][j][r];
                float s = v / (1.0f + __expf(-v));   // silu fused
                aout[(size_t)(b * TED_S + ig) * TED_DIM + d] = (bf16_t)s;
            }
        }
    }
}

// ---------------------------------------------------------------------------
// host side
// ---------------------------------------------------------------------------
extern "C" void kernel_launch(void* const* d_in, const int* in_sizes, int n_in,
                              void* d_out, int out_size, void* d_ws, size_t ws_size,
                              hipStream_t stream)
{
    const int*   tokens       = (const int*)d_in[0];
    const float* emb          = (const float*)d_in[1];
    const float* decay_norm_w = (const float*)d_in[2];
    const float* lambda_w     = (const float*)d_in[3];
    const float* quantity_w   = (const float*)d_in[4];
    const float* gate_w       = (const float*)d_in[5];
    const float* output_w     = (const float*)d_in[6];
    const float* ffn_norm_w   = (const float*)d_in[7];
    const float* w_h          = (const float*)d_in[8];
    const float* w_g          = (const float*)d_in[9];
    const float* w_o          = (const float*)d_in[10];
    const float* out_norm_w   = (const float*)d_in[11];

    constexpr int D = TED_DIM, H = TED_HID, L = TED_L, V = TED_VOCAB, R = TED_ROWS;

    char* ws = (char*)d_ws;
    size_t off = 0;
    auto alloc = [&](size_t bytes) -> char* {
        char* p = ws + off;
        off += (bytes + 255) & ~(size_t)255;
        return p;
    };
    bf16_t* emb_bf = (bf16_t*)alloc((size_t)V * D * 2);
    bf16_t* qw_bf  = (bf16_t*)alloc((size_t)L * D * D * 2);
    bf16_t* gw_bf  = (bf16_t*)alloc((size_t)L * D * D * 2);
    bf16_t* ow_bf  = (bf16_t*)alloc((size_t)L * D * D * 2);
    bf16_t* wh_bf  = (bf16_t*)alloc((size_t)L * H * D * 2);
    bf16_t* wg_bf  = (bf16_t*)alloc((size_t)L * H * D * 2);
    bf16_t* wo_bf  = (bf16_t*)alloc((size_t)L * D * H * 2);
    float*  x      = (float*)alloc((size_t)R * D * 4);
    bf16_t* h_bf   = (bf16_t*)alloc((size_t)R * D * 2);
    float*  nl2    = (float*)alloc((size_t)R * 4);
    bf16_t* qT_bf  = (bf16_t*)alloc((size_t)D * R * 2);
    float*  g_f32  = (float*)alloc((size_t)R * D * 4);
    bf16_t* a_bf   = (bf16_t*)alloc((size_t)R * D * 2);
    bf16_t* f_bf   = (bf16_t*)alloc((size_t)R * D * 2);
    bf16_t* u_bf   = (bf16_t*)alloc((size_t)R * H * 2);
    bf16_t* t_bf   = (bf16_t*)alloc((size_t)R * H * 2);
    if (off > ws_size) return;   // workspace too small -> leave d_out poisoned (visible failure)

    auto cvt = [&](const float* src, bf16_t* dst, size_t n) {
        int n4 = (int)(n / 4);
        cvt_kernel<<<dim3((n4 + 255) / 256), dim3(256), 0, stream>>>(src, dst, n4);
    };
    cvt(emb,        emb_bf, (size_t)V * D);
    cvt(quantity_w, qw_bf,  (size_t)L * D * D);
    cvt(gate_w,     gw_bf,  (size_t)L * D * D);
    cvt(output_w,   ow_bf,  (size_t)L * D * D);
    cvt(w_h,        wh_bf,  (size_t)L * H * D);
    cvt(w_g,        wg_bf,  (size_t)L * H * D);
    cvt(w_o,        wo_bf,  (size_t)L * D * H);

    embed_kernel<<<dim3(R), dim3(128), 0, stream>>>(tokens, emb, x);

    for (int l = 0; l < L; l++) {
        // h = rmsnorm(x, decay_norm_w[l]); nl2 = log_sigmoid(h . lambda)*log2e
        rmsnorm_kernel<<<dim3(R), dim3(256), 0, stream>>>(
            x, decay_norm_w + (size_t)l * D, lambda_w + (size_t)l * D, h_bf, nl2);
        // g = h @ gate_w^T  (fp32, used as multiplier)
        launch_gemm<64, 64, EPI_F32>(stream, h_bf, gw_bf + (size_t)l * D * D, R, D, D, g_f32);
        // qT = quantity_w @ h^T   -> [D, R] bf16 (transposed q for decay kernel)
        launch_gemm<64, 64, EPI_BF16>(stream, qw_bf + (size_t)l * D * D, h_bf, D, R, D,
                                      nullptr, qT_bf);
        // a = silu(decay @ q)
        decay_kernel<<<dim3(D / 128, TED_S / 64, TED_B), dim3(256), 0, stream>>>(qT_bf, nl2, a_bf);
        // x += (a @ output_w^T) * g
        launch_gemm<64, 64, EPI_GMUL_ADDX>(stream, a_bf, ow_bf + (size_t)l * D * D, R, D, D,
                                           nullptr, nullptr, g_f32, nullptr, x);
        // f = rmsnorm(x, ffn_norm_w[l])
        rmsnorm_kernel<<<dim3(R), dim3(256), 0, stream>>>(
            x, ffn_norm_w + (size_t)l * D, nullptr, f_bf, nullptr);
        // u = f @ w_h^T   [R, H] bf16
        launch_gemm<128, 128, EPI_BF16>(stream, f_bf, wh_bf + (size_t)l * H * D, R, H, D,
                                        nullptr, u_bf);
        // t = u * silu(f @ w_g^T)
        launch_gemm<128, 128, EPI_SILUMUL>(stream, f_bf, wg_bf + (size_t)l * H * D, R, H, D,
                                           nullptr, t_bf, nullptr, u_bf, nullptr);
        // x += t @ w_o^T
        launch_gemm<64, 64, EPI_ADDX>(stream, t_bf, wo_bf + (size_t)l * D * H, R, D, H,
                                      nullptr, nullptr, nullptr, nullptr, x);
    }

    // logits = rmsnorm(x, out_norm_w) @ emb^T  -> d_out fp32 [R, V]
    rmsnorm_kernel<<<dim3(R), dim3(256), 0, stream>>>(x, out_norm_w, nullptr, f_bf, nullptr);
    launch_gemm<128, 128, EPI_F32>(stream, f_bf, emb_bf, R, V, D, (float*)d_out);
}

// Round 2
// 1381.148 us; speedup vs baseline: 1.1692x; 1.0990x over previous
//
#include <hip/hip_runtime.h>
#include <cstdint>
#include <cstddef>

// ---------------------------------------------------------------------------
// TED forward on MI355X. Round 3: work-reduction + conflict-free LDS bundle.
//   - all MFMA kernels: BK=64, global_load_lds(16B) staging, T2-style XOR
//     swizzle done via pre-swizzled GLOBAL source (rule #21: linear LDS dest)
//   - FFN: u = f@wh and v = f@wg fused into one dual-B kernel, t = u*silu(v)
//     written directly (u never materialized)
//   - decay: wave-per-16-rows layout -> exp2 fragment work halved
//   - rmsnorm: wave-per-row, barrier-free (shfl_xor butterfly)
//   - weight fp32->bf16 cvt: single fused kernel
// ---------------------------------------------------------------------------

typedef __bf16 bf16_t;
typedef __bf16 bf16x2 __attribute__((ext_vector_type(2)));
typedef __bf16 bf16x4 __attribute__((ext_vector_type(4)));
typedef __bf16 bf16x8 __attribute__((ext_vector_type(8)));
typedef float  f32x4  __attribute__((ext_vector_type(4)));

#define TED_DIM   512
#define TED_HID   2048
#define TED_L     4
#define TED_VOCAB 32000
#define TED_B     2
#define TED_S     2048
#define TED_ROWS  4096   // B*S
#define LOG2E     1.44269504088896340736f

// async global -> LDS, 16 bytes per lane (m97 lever)
#define GLDS16(gp, lp)                                                  \
    __builtin_amdgcn_global_load_lds(                                   \
        (__attribute__((address_space(1))) void*)(gp),                  \
        (__attribute__((address_space(3))) void*)(lp), 16, 0, 0)

// ---------------------------------------------------------------------------
// fused fp32 -> bf16 convert of all 7 weight tensors (one dispatch)
// ---------------------------------------------------------------------------
struct CvtSeg { const float* src; bf16_t* dst; int n4; };
struct CvtArgs { CvtSeg seg[7]; };

__global__ __launch_bounds__(256) void cvt_all_kernel(CvtArgs a)
{
    int i0 = blockIdx.x * blockDim.x + threadIdx.x;
    int stride = gridDim.x * blockDim.x;
    #pragma unroll 1
    for (int s = 0; s < 7; s++) {
        const float4* src = (const float4*)a.seg[s].src;
        bf16x4* dst = (bf16x4*)a.seg[s].dst;
        int n4 = a.seg[s].n4;
        for (int i = i0; i < n4; i += stride) {
            float4 v = src[i];
            bf16x4 o;
            o[0] = (bf16_t)v.x; o[1] = (bf16_t)v.y; o[2] = (bf16_t)v.z; o[3] = (bf16_t)v.w;
            dst[i] = o;
        }
    }
}

// ---------------------------------------------------------------------------
// embedding gather: x[r,:] = emb[tok[r],:]   (fp32, 128 threads/row)
// ---------------------------------------------------------------------------
__global__ void embed_kernel(const int* __restrict__ tok, const float* __restrict__ emb,
                             float* __restrict__ x)
{
    int r = blockIdx.x;
    int t = threadIdx.x;           // 0..127, 4 floats each
    int id = tok[r];
    float4 v = *(const float4*)&emb[(size_t)id * TED_DIM + t * 4];
    *(float4*)&x[(size_t)r * TED_DIM + t * 4] = v;
}

// ---------------------------------------------------------------------------
// rmsnorm, wave-per-row (8 fp32/lane), barrier-free butterfly reduce.
// optional fused lambda projection -> nl2 = log_sigmoid(h.lam)*log2e
// 256 thr = 4 rows/block, grid = R/4
// ---------------------------------------------------------------------------
__global__ __launch_bounds__(256)
void rmsnorm_kernel(const float* __restrict__ x, const float* __restrict__ w,
                    const float* __restrict__ lam,
                    bf16_t* __restrict__ hout, float* __restrict__ nl2out)
{
    int t = threadIdx.x;
    int lane = t & 63, wv = t >> 6;
    int row = blockIdx.x * 4 + wv;
    const float* xr = x + (size_t)row * TED_DIM;

    float4 a = *(const float4*)&xr[lane * 8];
    float4 b = *(const float4*)&xr[lane * 8 + 4];
    float ss = a.x * a.x + a.y * a.y + a.z * a.z + a.w * a.w
             + b.x * b.x + b.y * b.y + b.z * b.z + b.w * b.w;
    #pragma unroll
    for (int off = 32; off; off >>= 1) ss += __shfl_xor(ss, off, 64);
    float scale = rsqrtf(ss * (1.0f / (float)TED_DIM) + 1e-6f);

    float4 wa = *(const float4*)&w[lane * 8];
    float4 wb = *(const float4*)&w[lane * 8 + 4];
    float h[8] = { a.x * scale * wa.x, a.y * scale * wa.y, a.z * scale * wa.z, a.w * scale * wa.w,
                   b.x * scale * wb.x, b.y * scale * wb.y, b.z * scale * wb.z, b.w * scale * wb.w };
    bf16x8 hb;
    #pragma unroll
    for (int k = 0; k < 8; k++) hb[k] = (bf16_t)h[k];
    *(bf16x8*)&hout[(size_t)row * TED_DIM + lane * 8] = hb;

    if (lam != nullptr) {
        float4 la = *(const float4*)&lam[lane * 8];
        float4 lb = *(const float4*)&lam[lane * 8 + 4];
        float p = h[0] * la.x + h[1] * la.y + h[2] * la.z + h[3] * la.w
                + h[4] * lb.x + h[5] * lb.y + h[6] * lb.z + h[7] * lb.w;
        #pragma unroll
        for (int off = 32; off; off >>= 1) p += __shfl_xor(p, off, 64);
        if (lane == 0) {
            float nl = fminf(p, 0.0f) - log1pf(__expf(-fabsf(p)));  // log_sigmoid(p)
            nl2out[row] = nl * LOG2E;
        }
    }
}

// ---------------------------------------------------------------------------
// bf16 GEMM, B^T layout: out[m,n] = sum_k A[m,k] * B[n,k]
// BK=64, 256 threads. Staging: global_load_lds 16B, LDS dest linear in t*16;
// XOR swizzle ((row&7) on 16B k-chunk) applied on the GLOBAL source address
// and again on the ds_read chunk -> conflict-free fragment reads (2-way).
// ---------------------------------------------------------------------------
enum { EPI_BF16 = 0, EPI_F32 = 1, EPI_GMUL_ADDX = 2, EPI_ADDX = 3 };

template <int BM, int BN, int EPI>
__global__ __launch_bounds__(256)
void gemm_bt(const bf16_t* __restrict__ A, const bf16_t* __restrict__ B,
             int M, int N, int K,
             float* __restrict__ outf, bf16_t* __restrict__ outb,
             const float* __restrict__ gmul, float* __restrict__ xres)
{
    constexpr int TM = BM / 32, TN = BN / 32;
    __shared__ __align__(16) bf16_t sA[BM * 64];
    __shared__ __align__(16) bf16_t sB[BN * 64];

    int t = threadIdx.x;
    int lane = t & 63, w = t >> 6;
    int quad = lane >> 4, l16 = lane & 15;
    int m0 = blockIdx.y * BM, n0 = blockIdx.x * BN;
    int wm = (w & 1) * (BM / 2), wn = (w >> 1) * (BN / 2);
    int srow = t >> 3;                    // 32 rows per issue (128B rows)
    int skc  = (t & 7) ^ (srow & 7);      // pre-swizzled source 16B chunk

    f32x4 acc[TM][TN] = {};

    for (int k0 = 0; k0 < K; k0 += 64) {
        #pragma unroll
        for (int i = 0; i < BM / 32; i++)
            GLDS16(&A[(size_t)(m0 + i * 32 + srow) * K + k0 + skc * 8],
                   &sA[(i * 32 + srow) * 64 + (t & 7) * 8]);
        #pragma unroll
        for (int i = 0; i < BN / 32; i++)
            GLDS16(&B[(size_t)(n0 + i * 32 + srow) * K + k0 + skc * 8],
                   &sB[(i * 32 + srow) * 64 + (t & 7) * 8]);
        __syncthreads();
        #pragma unroll
        for (int ks = 0; ks < 2; ks++) {
            int csw = ((ks * 4 + quad) ^ (l16 & 7)) * 8;   // swizzled read chunk
            bf16x8 af[TM], bfr[TN];
            #pragma unroll
            for (int i = 0; i < TM; i++)
                af[i] = *(const bf16x8*)&sA[(wm + i * 16 + l16) * 64 + csw];
            #pragma unroll
            for (int j = 0; j < TN; j++)
                bfr[j] = *(const bf16x8*)&sB[(wn + j * 16 + l16) * 64 + csw];
            #pragma unroll
            for (int i = 0; i < TM; i++)
                #pragma unroll
                for (int j = 0; j < TN; j++)
                    acc[i][j] = __builtin_amdgcn_mfma_f32_16x16x32_bf16(af[i], bfr[j], acc[i][j], 0, 0, 0);
        }
        __syncthreads();
    }

    // epilogue: C/D layout col = lane&15, row = quad*4 + r  [m89/m91 verified]
    #pragma unroll
    for (int i = 0; i < TM; i++) {
        #pragma unroll
        for (int j = 0; j < TN; j++) {
            int col = n0 + wn + j * 16 + l16;
            #pragma unroll
            for (int r = 0; r < 4; r++) {
                int rowg = m0 + wm + i * 16 + quad * 4 + r;
                size_t idx = (size_t)rowg * N + col;
                float v = acc[i][j][r];
                if constexpr (EPI == EPI_BF16) {
                    outb[idx] = (bf16_t)v;
                } else if constexpr (EPI == EPI_F32) {
                    outf[idx] = v;
                } else if constexpr (EPI == EPI_GMUL_ADDX) {
                    xres[idx] += v * gmul[idx];
                } else { // EPI_ADDX
                    xres[idx] += v;
                }
            }
        }
    }
}

template <int BM, int BN, int EPI>
static void launch_gemm(hipStream_t s, const bf16_t* A, const bf16_t* B,
                        int M, int N, int K,
                        float* outf = nullptr, bf16_t* outb = nullptr,
                        const float* gmul = nullptr, float* xres = nullptr)
{
    dim3 grid(N / BN, M / BM);
    gemm_bt<BM, BN, EPI><<<grid, 256, 0, s>>>(A, B, M, N, K, outf, outb, gmul, xres);
}

// ---------------------------------------------------------------------------
// fused FFN up-projection: t = (f @ wh^T) * silu(f @ wg^T), written bf16.
// BM=128 (rows of f), BN=64 (cols of H), BK=64. Dual B operands share A tile.
// ---------------------------------------------------------------------------
__global__ __launch_bounds__(256)
void gemm_ffn(const bf16_t* __restrict__ A, const bf16_t* __restrict__ Bh,
              const bf16_t* __restrict__ Bg, bf16_t* __restrict__ outb)
{
    constexpr int K = TED_DIM, N = TED_HID;   // 512, 2048
    __shared__ __align__(16) bf16_t sA[128 * 64];
    __shared__ __align__(16) bf16_t sH[64 * 64];
    __shared__ __align__(16) bf16_t sG[64 * 64];

    int t = threadIdx.x;
    int lane = t & 63, w = t >> 6;
    int quad = lane >> 4, l16 = lane & 15;
    int m0 = blockIdx.y * 128, n0 = blockIdx.x * 64;
    int wm = (w & 1) * 64, wn = (w >> 1) * 32;   // TM=4, TN=2
    int srow = t >> 3;
    int skc  = (t & 7) ^ (srow & 7);

    f32x4 aU[4][2] = {}, aV[4][2] = {};

    for (int k0 = 0; k0 < K; k0 += 64) {
        #pragma unroll
        for (int i = 0; i < 4; i++)
            GLDS16(&A[(size_t)(m0 + i * 32 + srow) * K + k0 + skc * 8],
                   &sA[(i * 32 + srow) * 64 + (t & 7) * 8]);
        #pragma unroll
        for (int i = 0; i < 2; i++)
            GLDS16(&Bh[(size_t)(n0 + i * 32 + srow) * K + k0 + skc * 8],
                   &sH[(i * 32 + srow) * 64 + (t & 7) * 8]);
        #pragma unroll
        for (int i = 0; i < 2; i++)
            GLDS16(&Bg[(size_t)(n0 + i * 32 + srow) * K + k0 + skc * 8],
                   &sG[(i * 32 + srow) * 64 + (t & 7) * 8]);
        __syncthreads();
        #pragma unroll
        for (int ks = 0; ks < 2; ks++) {
            int csw = ((ks * 4 + quad) ^ (l16 & 7)) * 8;
            bf16x8 af[4], bh[2], bg[2];
            #pragma unroll
            for (int i = 0; i < 4; i++)
                af[i] = *(const bf16x8*)&sA[(wm + i * 16 + l16) * 64 + csw];
            #pragma unroll
            for (int j = 0; j < 2; j++) {
                bh[j] = *(const bf16x8*)&sH[(wn + j * 16 + l16) * 64 + csw];
                bg[j] = *(const bf16x8*)&sG[(wn + j * 16 + l16) * 64 + csw];
            }
            #pragma unroll
            for (int i = 0; i < 4; i++) {
                #pragma unroll
                for (int j = 0; j < 2; j++) {
                    aU[i][j] = __builtin_amdgcn_mfma_f32_16x16x32_bf16(af[i], bh[j], aU[i][j], 0, 0, 0);
                    aV[i][j] = __builtin_amdgcn_mfma_f32_16x16x32_bf16(af[i], bg[j], aV[i][j], 0, 0, 0);
                }
            }
        }
        __syncthreads();
    }

    #pragma unroll
    for (int i = 0; i < 4; i++) {
        #pragma unroll
        for (int j = 0; j < 2; j++) {
            int col = n0 + wn + j * 16 + l16;
            #pragma unroll
            for (int r = 0; r < 4; r++) {
                int rowg = m0 + wm + i * 16 + quad * 4 + r;
                float u = aU[i][j][r], v = aV[i][j][r];
                float s = v / (1.0f + __expf(-v));
                outb[(size_t)rowg * N + col] = (bf16_t)(u * s);
            }
        }
    }
}

// ---------------------------------------------------------------------------
// decay einsum: aout[b*S+i, d] = silu( sum_{j<=i} exp2(nl2[b*S+j]*(i-j)) * q[b,j,d] )
// q supplied transposed: qT[d, b*S+j]. Wave-per-16-rows: TM=1, TN=8 -> exp2
// fragment work halved vs 2-wave-redundant layout. BK=32 (causal granularity).
// ---------------------------------------------------------------------------
__global__ __launch_bounds__(256)
void decay_kernel(const bf16_t* __restrict__ qT, const float* __restrict__ nl2,
                  bf16_t* __restrict__ aout)
{
    constexpr int BI = 64, BD = 128;
    __shared__ __align__(16) bf16_t sQ[BD * 32];

    int t = threadIdx.x;
    int lane = t & 63, w = t >> 6;
    int quad = lane >> 4, l16 = lane & 15;
    int d0 = blockIdx.x * BD;
    int i0 = blockIdx.y * BI;
    int b  = blockIdx.z;
    int srow = t >> 2;                    // 64 rows per issue (64B rows)
    int skc  = (t & 3) ^ (srow & 3);      // pre-swizzled source chunk (2-bit)

    f32x4 acc[8] = {};
    int mi = i0 + w * 16 + l16;           // this wave's output row for A-frag

    for (int j0 = 0; j0 < i0 + BI; j0 += 32) {
        #pragma unroll
        for (int i = 0; i < 2; i++)
            GLDS16(&qT[(size_t)(d0 + i * 64 + srow) * TED_ROWS + b * TED_S + j0 + skc * 8],
                   &sQ[(i * 64 + srow) * 32 + (t & 3) * 8]);
        // decay A-fragment in registers (overlaps the async DMA)
        float4 nA = *(const float4*)&nl2[b * TED_S + j0 + quad * 8];
        float4 nB = *(const float4*)&nl2[b * TED_S + j0 + quad * 8 + 4];
        float nn[8] = {nA.x, nA.y, nA.z, nA.w, nB.x, nB.y, nB.z, nB.w};
        bf16x8 af;
        #pragma unroll
        for (int jj = 0; jj < 8; jj++) {
            int j = j0 + quad * 8 + jj;
            int tt = mi - j;
            float dv = (tt >= 0) ? exp2f(nn[jj] * (float)tt) : 0.0f;
            af[jj] = (bf16_t)dv;
        }
        __syncthreads();
        int cq = (quad ^ (l16 & 3)) * 8;  // swizzled read chunk
        #pragma unroll
        for (int j = 0; j < 8; j++) {
            bf16x8 bfr = *(const bf16x8*)&sQ[(j * 16 + l16) * 32 + cq];
            acc[j] = __builtin_amdgcn_mfma_f32_16x16x32_bf16(af, bfr, acc[j], 0, 0, 0);
        }
        __syncthreads();
    }

    #pragma unroll
    for (int j = 0; j < 8; j++) {
        int d = d0 + j * 16 + l16;
        #pragma unroll
        for (int r = 0; r < 4; r++) {
            int ig = i0 + w * 16 + quad * 4 + r;
            float v = acc[j][r];
            float s = v / (1.0f + __expf(-v));   // silu fused
            aout[(size_t)(b * TED_S + ig) * TED_DIM + d] = (bf16_t)s;
        }
    }
}

// ---------------------------------------------------------------------------
// host side
// ---------------------------------------------------------------------------
extern "C" void kernel_launch(void* const* d_in, const int* in_sizes, int n_in,
                              void* d_out, int out_size, void* d_ws, size_t ws_size,
                              hipStream_t stream)
{
    const int*   tokens       = (const int*)d_in[0];
    const float* emb          = (const float*)d_in[1];
    const float* decay_norm_w = (const float*)d_in[2];
    const float* lambda_w     = (const float*)d_in[3];
    const float* quantity_w   = (const float*)d_in[4];
    const float* gate_w       = (const float*)d_in[5];
    const float* output_w     = (const float*)d_in[6];
    const float* ffn_norm_w   = (const float*)d_in[7];
    const float* w_h          = (const float*)d_in[8];
    const float* w_g          = (const float*)d_in[9];
    const float* w_o          = (const float*)d_in[10];
    const float* out_norm_w   = (const float*)d_in[11];

    constexpr int D = TED_DIM, H = TED_HID, L = TED_L, V = TED_VOCAB, R = TED_ROWS;

    char* ws = (char*)d_ws;
    size_t off = 0;
    auto alloc = [&](size_t bytes) -> char* {
        char* p = ws + off;
        off += (bytes + 255) & ~(size_t)255;
        return p;
    };
    bf16_t* emb_bf = (bf16_t*)alloc((size_t)V * D * 2);
    bf16_t* qw_bf  = (bf16_t*)alloc((size_t)L * D * D * 2);
    bf16_t* gw_bf  = (bf16_t*)alloc((size_t)L * D * D * 2);
    bf16_t* ow_bf  = (bf16_t*)alloc((size_t)L * D * D * 2);
    bf16_t* wh_bf  = (bf16_t*)alloc((size_t)L * H * D * 2);
    bf16_t* wg_bf  = (bf16_t*)alloc((size_t)L * H * D * 2);
    bf16_t* wo_bf  = (bf16_t*)alloc((size_t)L * D * H * 2);
    float*  x      = (float*)alloc((size_t)R * D * 4);
    bf16_t* h_bf   = (bf16_t*)alloc((size_t)R * D * 2);
    float*  nl2    = (float*)alloc((size_t)R * 4);
    bf16_t* qT_bf  = (bf16_t*)alloc((size_t)D * R * 2);
    float*  g_f32  = (float*)alloc((size_t)R * D * 4);
    bf16_t* a_bf   = (bf16_t*)alloc((size_t)R * D * 2);
    bf16_t* f_bf   = (bf16_t*)alloc((size_t)R * D * 2);
    bf16_t* t_bf   = (bf16_t*)alloc((size_t)R * H * 2);
    if (off > ws_size) return;   // workspace too small -> visible failure

    CvtArgs ca;
    ca.seg[0] = { emb,        emb_bf, (int)((size_t)V * D / 4) };
    ca.seg[1] = { quantity_w, qw_bf,  (int)((size_t)L * D * D / 4) };
    ca.seg[2] = { gate_w,     gw_bf,  (int)((size_t)L * D * D / 4) };
    ca.seg[3] = { output_w,   ow_bf,  (int)((size_t)L * D * D / 4) };
    ca.seg[4] = { w_h,        wh_bf,  (int)((size_t)L * H * D / 4) };
    ca.seg[5] = { w_g,        wg_bf,  (int)((size_t)L * H * D / 4) };
    ca.seg[6] = { w_o,        wo_bf,  (int)((size_t)L * D * H / 4) };
    cvt_all_kernel<<<dim3(2048), dim3(256), 0, stream>>>(ca);

    embed_kernel<<<dim3(R), dim3(128), 0, stream>>>(tokens, emb, x);

    for (int l = 0; l < L; l++) {
        // h = rmsnorm(x, decay_norm_w[l]); nl2 = log_sigmoid(h.lambda)*log2e
        rmsnorm_kernel<<<dim3(R / 4), dim3(256), 0, stream>>>(
            x, decay_norm_w + (size_t)l * D, lambda_w + (size_t)l * D, h_bf, nl2);
        // g = h @ gate_w^T  (fp32 multiplier)
        launch_gemm<64, 64, EPI_F32>(stream, h_bf, gw_bf + (size_t)l * D * D, R, D, D, g_f32);
        // qT = quantity_w @ h^T   -> [D, R] bf16
        launch_gemm<64, 64, EPI_BF16>(stream, qw_bf + (size_t)l * D * D, h_bf, D, R, D,
                                      nullptr, qT_bf);
        // a = silu(decay @ q)
        decay_kernel<<<dim3(D / 128, TED_S / 64, TED_B), dim3(256), 0, stream>>>(qT_bf, nl2, a_bf);
        // x += (a @ output_w^T) * g
        launch_gemm<64, 64, EPI_GMUL_ADDX>(stream, a_bf, ow_bf + (size_t)l * D * D, R, D, D,
                                           nullptr, nullptr, g_f32, x);
        // f = rmsnorm(x, ffn_norm_w[l])
        rmsnorm_kernel<<<dim3(R / 4), dim3(256), 0, stream>>>(
            x, ffn_norm_w + (size_t)l * D, nullptr, f_bf, nullptr);
        // t = (f @ w_h^T) * silu(f @ w_g^T)   (fused, u kept fp32 in-register)
        gemm_ffn<<<dim3(H / 64, R / 128), dim3(256), 0, stream>>>(
            f_bf, wh_bf + (size_t)l * H * D, wg_bf + (size_t)l * H * D, t_bf);
        // x += t @ w_o^T
        launch_gemm<64, 64, EPI_ADDX>(stream, t_bf, wo_bf + (size_t)l * D * H, R, D, H,
                                      nullptr, nullptr, nullptr, x);
    }

    // logits = rmsnorm(x, out_norm_w) @ emb^T  -> d_out fp32 [R, V]
    rmsnorm_kernel<<<dim3(R / 4), dim3(256), 0, stream>>>(x, out_norm_w, nullptr, f_bf, nullptr);
    launch_gemm<128, 128, EPI_F32>(stream, f_bf, emb_bf, R, V, D, (float*)d_out);
}